// Round 10
// baseline (93.685 us; speedup 1.0000x reference)
//
#include <hip/hip_runtime.h>
#include <hip/hip_bf16.h>

// Problem: B=128, M=256, T=512, N=512
// C[m][k] = sum_t X[b][t][n]*We2[t][k], m=(b,n);  e = sum_k tanh(C+g)*v; softmax_n.
// k split over 4 blocks (kblk) -> partials Ep[4] summed in softmax.
// KEY CHANGE (R10): X is staged by global_load_lds DMA (unsinkable, counted
// vmcnt pipeline, 2-step cover) as raw f32 with XOR-chunk-swizzled source;
// f32->f16 cvt happens on the LDS-read side under the MFMAs.

typedef _Float16 half8 __attribute__((ext_vector_type(8)));
typedef float floatx4 __attribute__((ext_vector_type(4)));

#define GLOAD_LDS16(gp, lp) __builtin_amdgcn_global_load_lds(                  \
    (const __attribute__((address_space(1))) void*)(const void*)(gp),          \
    (__attribute__((address_space(3))) void*)(void*)(lp), 16, 0, 0)

__device__ __forceinline__ float fast_tanh(float x) {
    float cx = fminf(15.0f, fmaxf(-15.0f, x));
    float e = __expf(2.0f * cx);
    return (e - 1.0f) * __fdividef(1.0f, e + 1.0f);
}

// ---------------- K0: Bf chunks per (kblk, ts): 4096 f16 ----------------
// unit u = c8*64 + l holds We2[ts*32 + (l>>4)*8 + j][kblk*128 + c8*16 + (l&15)]
__global__ __launch_bounds__(256) void k_prep_b(const float* __restrict__ We2,
                                                _Float16* __restrict__ Bf) {
    __shared__ float w2[32][133];
    const int kblk = blockIdx.x >> 4, ts = blockIdx.x & 15;
    for (int idx = threadIdx.x; idx < 32 * 128; idx += 256) {
        int tr = idx >> 7, kc = idx & 127;
        w2[tr][kc] = We2[(ts * 32 + tr) * 512 + kblk * 128 + kc];   // coalesced
    }
    __syncthreads();
    _Float16* dst = Bf + (size_t)blockIdx.x * 4096;
#pragma unroll
    for (int i = 0; i < 2; ++i) {
        int u = threadIdx.x + (i << 8);          // 0..511
        int c8 = u >> 6, l = u & 63;
        int tl = (l >> 4) * 8, kl = c8 * 16 + (l & 15);
        half8 h;
#pragma unroll
        for (int j = 0; j < 8; ++j) h[j] = (_Float16)w2[tl + j][kl];
        *(half8*)&dst[u * 8] = h;                // coalesced
    }
}

// ---------------- K1: g[b][k] = hc@We1 + be1 + be2 ----------------
__global__ __launch_bounds__(256) void k_hs(const float* __restrict__ hidden,
                                            const float* __restrict__ cell,
                                            const float* __restrict__ We1,
                                            const float* __restrict__ be1,
                                            const float* __restrict__ be2,
                                            float* __restrict__ g) {
    __shared__ __align__(16) float hcl[8][512];
    __shared__ float red[4][8][64];
    const int b0 = (blockIdx.x >> 3) << 3;
    const int k0 = (blockIdx.x & 7) << 6;
    for (int idx = threadIdx.x; idx < 8 * 512; idx += 256) {
        int bi = idx >> 9, j = idx & 511;
        hcl[bi][j] = (j < 256) ? hidden[(b0 + bi) * 256 + j]
                               : cell[(b0 + bi) * 256 + j - 256];
    }
    __syncthreads();
    const int kl = threadIdx.x & 63;
    const int jc = threadIdx.x >> 6;
    const int k  = k0 + kl;
    float acc[8] = {};
    for (int j = jc * 128; j < jc * 128 + 128; j += 4) {
        float w0 = We1[(j + 0) * 512 + k];
        float w1 = We1[(j + 1) * 512 + k];
        float w2 = We1[(j + 2) * 512 + k];
        float w3 = We1[(j + 3) * 512 + k];
#pragma unroll
        for (int bi = 0; bi < 8; ++bi) {
            float4 h = *(const float4*)&hcl[bi][j];
            acc[bi] += h.x * w0 + h.y * w1 + h.z * w2 + h.w * w3;
        }
    }
#pragma unroll
    for (int bi = 0; bi < 8; ++bi) red[jc][bi][kl] = acc[bi];
    __syncthreads();
    for (int idx = threadIdx.x; idx < 512; idx += 256) {
        int bi = idx >> 6, kk = idx & 63;
        float s = red[0][bi][kk] + red[1][bi][kk] + red[2][bi][kk] + red[3][bi][kk];
        int kg = k0 + kk;
        g[(b0 + bi) * 512 + kg] = s + be1[kg] + be2[kg];
    }
}

// ---------------- K2: GEMM 128m x 128k, BK=32, all-DMA staging ----------------
// grid 2048 = 512 mt x 4 kblk (XCD swizzle keeps kblk-siblings on one XCD).
// 256 thr = 4 waves (2m x 2k); wave acc 4x4 -> 16 MFMA/step; 16 steps.
// X tile [32t][32c][4r] f32 DMA'd with source-chunk XOR swizzle (c^2*(t>>3));
// B chunk frag-linear f16 DMA'd.  3 LDS bufs, counted vmcnt(6), one barrier
// per step (m201 discipline: wait -> barrier -> reads -> issue -> MFMA).
__global__ __launch_bounds__(256, 2) void k_main(const float* __restrict__ X,
                                                 const _Float16* __restrict__ Bf,
                                                 const float* __restrict__ g,
                                                 const float* __restrict__ vvec,
                                                 float* __restrict__ Ep) {
    __shared__ __align__(16) float    Xs[3][4096];   // 48 KB
    __shared__ __align__(16) _Float16 Bs[3][4096];   // 24 KB
    const int tid  = threadIdx.x;
    const int lane = tid & 63;
    const int wv   = tid >> 6;        // 0..3
    const int l16  = lane & 15;
    const int lhi  = lane >> 4;       // 0..3
    const int logical = ((blockIdx.x & 7) << 8) | (blockIdx.x >> 3);
    const int mt   = logical >> 2;
    const int kblk = logical & 3;
    const int b    = mt >> 2;
    const int n0   = (mt & 3) << 7;
    const int mw   = wv >> 1;         // m-half
    const int kw   = wv & 1;          // k-half

    const float* Xg = X + (size_t)b * 262144 + n0;
    const _Float16* Bg = Bf + (size_t)kblk * 65536;   // 16 chunks x 4096

    // X-DMA lane geometry: instr p covers t-rows wv*8+p*2+{0,1}; lane chunk
    // c_slot = lane&31 receives global chunk c_g = c_slot ^ 2*((t>>3)&3).
    int xt[4], xcg[4];
#pragma unroll
    for (int p = 0; p < 4; ++p) {
        int t = wv * 8 + p * 2 + (lane >> 5);
        xt[p]  = t;
        xcg[p] = (lane & 31) ^ (2 * ((t >> 3) & 3));
    }
    // A-frag read offsets (f32 elems): row t = lhi*8+j, chunk c = mw*16+mf*4+q
    const int q = l16 >> 2, r = l16 & 3;
    int xoff[4];
#pragma unroll
    for (int mf = 0; mf < 4; ++mf) {
        int c = mw * 16 + mf * 4 + q;
        xoff[mf] = lhi * 1024 + ((c ^ (2 * lhi)) << 2) + r;
    }

#define XDMA(ts_, bf_)                                                         \
    { _Pragma("unroll")                                                        \
      for (int p = 0; p < 4; ++p)                                              \
          GLOAD_LDS16(Xg + (size_t)((ts_) * 32 + xt[p]) * 512 + xcg[p] * 4,    \
                      &Xs[bf_][(wv * 8 + p * 2) * 128 + lane * 4]); }
#define BDMA(ts_, bf_)                                                         \
    { _Pragma("unroll")                                                        \
      for (int qq = 0; qq < 2; ++qq)                                           \
          GLOAD_LDS16(Bg + (size_t)(ts_) * 4096 + ((wv * 2 + qq) * 64 + lane) * 8, \
                      &Bs[bf_][((wv * 2 + qq) * 64 + lane) * 8]); }

    // ---- prologue: tiles 0,1 in flight (12 DMA instrs/wave outstanding)
    XDMA(0, 0); BDMA(0, 0);
    XDMA(1, 1); BDMA(1, 1);

    floatx4 acc[4][4];
#pragma unroll
    for (int a = 0; a < 4; ++a)
#pragma unroll
        for (int c = 0; c < 4; ++c) acc[a][c] = (floatx4){0.f, 0.f, 0.f, 0.f};

#pragma unroll
    for (int ts = 0; ts < 16; ++ts) {
        const int bf = ts % 3;
        // tile ts complete (oldest 6); tile ts+1 stays in flight
        if (ts < 15) asm volatile("s_waitcnt vmcnt(6)" ::: "memory");
        else         asm volatile("s_waitcnt vmcnt(0)" ::: "memory");
        __builtin_amdgcn_sched_barrier(0);
        __builtin_amdgcn_s_barrier();     // all waves' tile-ts data in LDS;
        __builtin_amdgcn_sched_barrier(0); // also: all ts-1 reads done
        // fragment reads (A: 8 x b32 swizzled 2-way; B: b128 linear) + cvt
        half8 af[4], bfr[4];
#pragma unroll
        for (int mf = 0; mf < 4; ++mf)
#pragma unroll
            for (int j = 0; j < 8; ++j)
                af[mf][j] = (_Float16)Xs[bf][xoff[mf] + j * 128];
#pragma unroll
        for (int nf = 0; nf < 4; ++nf)
            bfr[nf] = *(const half8*)&Bs[bf][((kw * 4 + nf) * 64 + lane) * 8];
        // issue tile ts+2 into buf freed by step ts-1's readers
        if (ts < 14) {
            XDMA(ts + 2, (ts + 2) % 3);
            BDMA(ts + 2, (ts + 2) % 3);
        }
        __builtin_amdgcn_sched_barrier(0);
        __builtin_amdgcn_s_setprio(1);
#pragma unroll
        for (int mf = 0; mf < 4; ++mf)
#pragma unroll
            for (int nf = 0; nf < 4; ++nf)
                acc[mf][nf] = __builtin_amdgcn_mfma_f32_16x16x32_f16(
                    af[mf], bfr[nf], acc[mf][nf], 0, 0, 0);
        __builtin_amdgcn_s_setprio(0);
    }

    // ---- fused epilogue ----
    // C layout: row m = mw*64+mf*16+lhi*4+rr ; col k_local = kw*64+nf*16+l16
    const float* gb = g + b * 512 + kblk * 128;
    const float* vb = vvec + kblk * 128;
    float sl[4][4];
#pragma unroll
    for (int mf = 0; mf < 4; ++mf)
#pragma unroll
        for (int rr = 0; rr < 4; ++rr) sl[mf][rr] = 0.f;
#pragma unroll
    for (int nf = 0; nf < 4; ++nf) {
        const int klc = kw * 64 + nf * 16 + l16;
        const float gv  = gb[klc];
        const float vvl = vb[klc];
#pragma unroll
        for (int mf = 0; mf < 4; ++mf)
#pragma unroll
            for (int rr = 0; rr < 4; ++rr)
                sl[mf][rr] += fast_tanh(acc[mf][nf][rr] + gv) * vvl;
    }
#pragma unroll
    for (int mf = 0; mf < 4; ++mf)
#pragma unroll
        for (int rr = 0; rr < 4; ++rr) {
            float x = sl[mf][rr];
            x += __shfl_xor(x, 1);
            x += __shfl_xor(x, 2);
            x += __shfl_xor(x, 4);
            x += __shfl_xor(x, 8);
            sl[mf][rr] = x;
        }
    __syncthreads();                       // loop fully drained -> overlay
    float* ered = (float*)&Xs[0][0];       // [2 kw][128 m]
    if (l16 == 0) {
#pragma unroll
        for (int mf = 0; mf < 4; ++mf)
#pragma unroll
            for (int rr = 0; rr < 4; ++rr)
                ered[kw * 128 + mw * 64 + mf * 16 + lhi * 4 + rr] = sl[mf][rr];
    }
    __syncthreads();
    if (tid < 128) {
        float e = ered[tid] + ered[128 + tid];
        Ep[(size_t)kblk * 65536 + b * 512 + n0 + tid] = e;
    }
#undef XDMA
#undef BDMA
}

// ---------------- K3: softmax over n (512), summing 4 k-partials ------------
__global__ __launch_bounds__(256) void k_softmax(const float* __restrict__ Ep,
                                                 float* __restrict__ out) {
    __shared__ float rmax[4], rsum[4];
    const int b = blockIdx.x;
    const int tid = threadIdx.x;
    float e0 = Ep[b * 512 + tid] + Ep[65536 + b * 512 + tid] +
               Ep[131072 + b * 512 + tid] + Ep[196608 + b * 512 + tid];
    float e1 = Ep[b * 512 + 256 + tid] + Ep[65536 + b * 512 + 256 + tid] +
               Ep[131072 + b * 512 + 256 + tid] + Ep[196608 + b * 512 + 256 + tid];
    float m = fmaxf(e0, e1);
    for (int o = 32; o > 0; o >>= 1) m = fmaxf(m, __shfl_xor(m, o));
    if ((tid & 63) == 0) rmax[tid >> 6] = m;
    __syncthreads();
    m = fmaxf(fmaxf(rmax[0], rmax[1]), fmaxf(rmax[2], rmax[3]));
    float p0 = __expf(e0 - m), p1 = __expf(e1 - m);
    float ss = p0 + p1;
    for (int o = 32; o > 0; o >>= 1) ss += __shfl_xor(ss, o);
    if ((tid & 63) == 0) rsum[tid >> 6] = ss;
    __syncthreads();
    ss = rsum[0] + rsum[1] + rsum[2] + rsum[3];
    float inv = __fdividef(1.0f, ss);
    out[b * 512 + tid] = p0 * inv;
    out[b * 512 + 256 + tid] = p1 * inv;
}

extern "C" void kernel_launch(void* const* d_in, const int* in_sizes, int n_in,
                              void* d_out, int out_size, void* d_ws, size_t ws_size,
                              hipStream_t stream) {
    const float* hidden = (const float*)d_in[0];
    const float* cell   = (const float*)d_in[1];
    const float* X      = (const float*)d_in[2];
    const float* We1    = (const float*)d_in[3];
    const float* be1    = (const float*)d_in[4];
    const float* We2    = (const float*)d_in[5];
    const float* be2    = (const float*)d_in[6];
    const float* v      = (const float*)d_in[7];
    float* out = (float*)d_out;

    char* ws = (char*)d_ws;
    _Float16* Bf = (_Float16*)ws;                        // 64*4096*2   = 524288 B
    float* g     = (float*)(ws + 524288);                // 128*512*4   = 262144 B
    float* Ep    = (float*)(ws + 786432);                // 4*128*512*4 = 1048576 B

    k_prep_b<<<64, 256, 0, stream>>>(We2, Bf);
    k_hs<<<128, 256, 0, stream>>>(hidden, cell, We1, be1, be2, g);
    k_main<<<2048, 256, 0, stream>>>(X, Bf, g, v, Ep);
    k_softmax<<<128, 256, 0, stream>>>(Ep, out);
}

// Round 12
// 83.234 us; speedup vs baseline: 1.1256x; 1.1256x over previous
//
#include <hip/hip_runtime.h>
#include <hip/hip_bf16.h>

// Problem: B=128, M=256, T=512, N=512
// D[k][n] = sum_t We2T[k][t] * X[t][n] per b;  e[b,n] = sum_k tanh(D+g)*v[k];
// attn = softmax_n(e).  k split in 2 block-halves (kblk) -> partials summed
// in softmax (k-sum is outside tanh).

typedef _Float16 half8 __attribute__((ext_vector_type(8)));
typedef _Float16 half2v __attribute__((ext_vector_type(2)));
typedef float floatx4 __attribute__((ext_vector_type(4)));

#define GLOAD_LDS16(gp, lp) __builtin_amdgcn_global_load_lds(                  \
    (const __attribute__((address_space(1))) void*)(const void*)(gp),          \
    (__attribute__((address_space(3))) void*)(void*)(lp), 16, 0, 0)

__device__ __forceinline__ float fast_tanh(float x) {
    float cx = fminf(15.0f, fmaxf(-15.0f, x));
    float e = __expf(2.0f * cx);
    return (e - 1.0f) * __fdividef(1.0f, e + 1.0f);
}

// ---------------- K0: Af slabs (A = We2^T f16, frag-linear) ----------------
// slab ts (32 t), chunk c = k-16-group (0..31), lane l: holds
// A[k=c*16+(l&15)][t=ts*32+(l>>4)*8+j], j=0..7.  Elem ofs: ts*16384+c*512+l*8.
__global__ __launch_bounds__(256) void k_prep_a(const float* __restrict__ We2,
                                                _Float16* __restrict__ Af) {
    __shared__ float w2[32][512];
    const int ts = blockIdx.x;
    for (int idx = threadIdx.x; idx < 32 * 512; idx += 256) {
        int tl = idx >> 9, k = idx & 511;
        w2[tl][k] = We2[(ts * 32 + tl) * 512 + k];
    }
    __syncthreads();
    for (int item = threadIdx.x; item < 32 * 64; item += 256) {
        int c = item >> 6, l = item & 63;
        int k  = c * 16 + (l & 15);
        int tl = (l >> 4) * 8;
        half8 h;
#pragma unroll
        for (int j = 0; j < 8; ++j) h[j] = (_Float16)w2[tl + j][k];
        *(half8*)&Af[(((size_t)ts * 32 + c) * 64 + l) * 8] = h;
    }
}

// ---------------- K1: g[b][k] = hc@We1 + be1 + be2 ----------------
__global__ __launch_bounds__(256) void k_hs(const float* __restrict__ hidden,
                                            const float* __restrict__ cell,
                                            const float* __restrict__ We1,
                                            const float* __restrict__ be1,
                                            const float* __restrict__ be2,
                                            float* __restrict__ g) {
    __shared__ __align__(16) float hcl[8][512];
    __shared__ float red[4][8][64];
    const int b0 = (blockIdx.x >> 3) << 3;
    const int k0 = (blockIdx.x & 7) << 6;
    for (int idx = threadIdx.x; idx < 8 * 512; idx += 256) {
        int bi = idx >> 9, j = idx & 511;
        hcl[bi][j] = (j < 256) ? hidden[(b0 + bi) * 256 + j]
                               : cell[(b0 + bi) * 256 + j - 256];
    }
    __syncthreads();
    const int kl = threadIdx.x & 63;
    const int jc = threadIdx.x >> 6;
    const int k  = k0 + kl;
    float acc[8] = {};
    for (int j = jc * 128; j < jc * 128 + 128; j += 4) {
        float w0 = We1[(j + 0) * 512 + k];
        float w1 = We1[(j + 1) * 512 + k];
        float w2 = We1[(j + 2) * 512 + k];
        float w3 = We1[(j + 3) * 512 + k];
#pragma unroll
        for (int bi = 0; bi < 8; ++bi) {
            float4 h = *(const float4*)&hcl[bi][j];
            acc[bi] += h.x * w0 + h.y * w1 + h.z * w2 + h.w * w3;
        }
    }
#pragma unroll
    for (int bi = 0; bi < 8; ++bi) red[jc][bi][kl] = acc[bi];
    __syncthreads();
    for (int idx = threadIdx.x; idx < 512; idx += 256) {
        int bi = idx >> 6, kk = idx & 63;
        float s = red[0][bi][kk] + red[1][bi][kk] + red[2][bi][kk] + red[3][bi][kk];
        int kg = k0 + kk;
        g[(b0 + bi) * 512 + kg] = s + be1[kg] + be2[kg];
    }
}

// ---------------- K2: fused GEMM, BK=64, 32 MFMA/wave/step ----------------
// grid 2048 = 128b x 8nt(64) x 2kblk (XCD-paired).  256 thr = 4 waves; wave
// wv owns k [kblk*256+wv*64, +64) x n 64 -> acc 4x4; 2 ko-halves/step -> 32
// MFMA/wave/step, 8 steps.  X tile [64t][64n] f32 DMA'd (source chunk-XOR
// c^=((t>>3)&3)<<1; same XOR on read => 2-way banks, DMA dest linear).
// A frag-direct global->reg from L2-hot Af (issued after DMAs; auto-waits
// leave DMAs in flight).  3 X bufs, counted vmcnt(4).  LDS 48 KB -> 3
// blocks/CU = 12 waves/CU.
__global__ __launch_bounds__(256, 3) void k_main(const float* __restrict__ X,
                                                 const _Float16* __restrict__ Af,
                                                 const float* __restrict__ g,
                                                 const float* __restrict__ vvec,
                                                 float* __restrict__ Ep) {
    __shared__ __align__(16) float Xs[3][4096];       // 3 x 16 KiB
    const int tid  = threadIdx.x;
    const int lane = tid & 63;
    const int wv   = tid >> 6;        // 0..3
    const int l16  = lane & 15;
    const int lhi  = lane >> 4;       // 0..3
    const int logical = ((blockIdx.x & 7) << 8) | (blockIdx.x >> 3);
    const int kblk = logical & 1;
    const int nt   = (logical >> 1) & 7;
    const int b    = logical >> 4;
    const int n0   = nt << 6;

    const float* Xg = X + (size_t)b * 262144 + n0;
    // A base: chunk c = kblk*16 + wv*4 + kf
    const _Float16* AgW = Af + (size_t)(kblk * 16 + wv * 4) * 512 + (size_t)lane * 8;

    // X-DMA per-lane geometry (4 instrs/wave/step; each 1 KB = 4 t-rows)
    int xsrc[4], xdst[4];
#pragma unroll
    for (int p = 0; p < 4; ++p) {
        int t_loc = (wv << 4) + (p << 2) + (lane >> 4);
        int c_g   = (lane & 15) ^ (((t_loc >> 3) & 3) << 1);
        xsrc[p] = t_loc * 512 + c_g * 4;                  // f32 elems
        xdst[p] = ((wv << 4) + (p << 2)) * 64 + lane * 4; // linear: base+lane*16B
    }
#define XDMA(s_, b_)                                                           \
    { _Pragma("unroll")                                                        \
      for (int p = 0; p < 4; ++p)                                              \
          GLOAD_LDS16(Xg + (size_t)(s_) * 32768 + xsrc[p], &Xs[b_][xdst[p]]); }

    // B-frag read offsets (word units), j=0,ko=0; +ko*2048 +j*64 at use
    const int q = l16 >> 2, r = l16 & 3;
    int boff[4];
#pragma unroll
    for (int nf = 0; nf < 4; ++nf)
        boff[nf] = lhi * 512 + ((((nf << 2) + q) ^ (lhi << 1)) << 2) + r;

    // ---- prologue: tiles 0,1 in flight (8 DMA/wave outstanding)
    XDMA(0, 0);
    XDMA(1, 1);

    floatx4 acc[4][4];
#pragma unroll
    for (int a = 0; a < 4; ++a)
#pragma unroll
        for (int c = 0; c < 4; ++c) acc[a][c] = (floatx4){0.f, 0.f, 0.f, 0.f};

#pragma unroll
    for (int s = 0; s < 8; ++s) {
        const int buf = s % 3;
        // X(s) landed; X(s+1) stays in flight
        if (s < 7) asm volatile("s_waitcnt vmcnt(4)" ::: "memory");
        else       asm volatile("s_waitcnt vmcnt(0)" ::: "memory");
        asm volatile("s_waitcnt lgkmcnt(0)" ::: "memory");  // drain old reads
        __builtin_amdgcn_sched_barrier(0);
        __builtin_amdgcn_s_barrier();
        __builtin_amdgcn_sched_barrier(0);
        // issue X(s+2) BEFORE A-loads so A auto-waits leave DMAs in flight
        if (s + 2 < 8) XDMA(s + 2, (s + 2) % 3);
#pragma unroll
        for (int ko = 0; ko < 2; ++ko) {
            half8 af[4];
#pragma unroll
            for (int kf = 0; kf < 4; ++kf)
                af[kf] = *(const half8*)
                    (AgW + (size_t)(2 * s + ko) * 16384 + kf * 512);
            half8 bf[4];
#pragma unroll
            for (int nf = 0; nf < 4; ++nf) {
                union { half2v h2[4]; half8 h8; } u;
#pragma unroll
                for (int m = 0; m < 4; ++m) {
                    float f0 = Xs[buf][boff[nf] + ko * 2048 + (2 * m) * 64];
                    float f1 = Xs[buf][boff[nf] + ko * 2048 + (2 * m + 1) * 64];
                    u.h2[m] = __builtin_bit_cast(half2v,
                                  __builtin_amdgcn_cvt_pkrtz(f0, f1));
                }
                bf[nf] = u.h8;
            }
            __builtin_amdgcn_s_setprio(1);
#pragma unroll
            for (int kf = 0; kf < 4; ++kf)
#pragma unroll
                for (int nf = 0; nf < 4; ++nf)
                    acc[kf][nf] = __builtin_amdgcn_mfma_f32_16x16x32_f16(
                        af[kf], bf[nf], acc[kf][nf], 0, 0, 0);
            __builtin_amdgcn_s_setprio(0);
        }
    }
#undef XDMA

    // ---- fused epilogue: s[n] = sum_{k in 64-slice} tanh(acc+g)*v
    // C/D: col n = l16, row k = lhi*4 + reg (within 16-group kf)
    const float* gb = g + b * 512;
    float sacc[4] = {0.f, 0.f, 0.f, 0.f};
#pragma unroll
    for (int kf = 0; kf < 4; ++kf) {
        const int kb = kblk * 256 + wv * 64 + kf * 16 + lhi * 4;
        float g0 = gb[kb + 0], g1 = gb[kb + 1], g2 = gb[kb + 2], g3 = gb[kb + 3];
        float v0 = vvec[kb + 0], v1 = vvec[kb + 1], v2 = vvec[kb + 2], v3 = vvec[kb + 3];
#pragma unroll
        for (int nf = 0; nf < 4; ++nf) {
            sacc[nf] += fast_tanh(acc[kf][nf][0] + g0) * v0;
            sacc[nf] += fast_tanh(acc[kf][nf][1] + g1) * v1;
            sacc[nf] += fast_tanh(acc[kf][nf][2] + g2) * v2;
            sacc[nf] += fast_tanh(acc[kf][nf][3] + g3) * v3;
        }
    }
#pragma unroll
    for (int nf = 0; nf < 4; ++nf) {
        sacc[nf] += __shfl_xor(sacc[nf], 16);
        sacc[nf] += __shfl_xor(sacc[nf], 32);
    }
    __syncthreads();                 // loop fully drained -> overlay on Xs
    float* ered = (float*)&Xs[0][0]; // [4 waves][64 n]
    if (lane < 16) {
#pragma unroll
        for (int nf = 0; nf < 4; ++nf) ered[wv * 64 + nf * 16 + l16] = sacc[nf];
    }
    __syncthreads();
    if (tid < 64) {
        float e = ered[tid] + ered[64 + tid] + ered[128 + tid] + ered[192 + tid];
        Ep[(size_t)kblk * 65536 + b * 512 + n0 + tid] = e;
    }
}

// ---------------- K3: softmax over n (512), summing 2 k-partials ------------
__global__ __launch_bounds__(256) void k_softmax(const float* __restrict__ Ep,
                                                 float* __restrict__ out) {
    __shared__ float rmax[4], rsum[4];
    const int b = blockIdx.x;
    const int tid = threadIdx.x;
    const float* E0 = Ep;
    const float* E1 = Ep + 65536;
    float e0 = E0[b * 512 + tid] + E1[b * 512 + tid];
    float e1 = E0[b * 512 + 256 + tid] + E1[b * 512 + 256 + tid];
    float m = fmaxf(e0, e1);
    for (int o = 32; o > 0; o >>= 1) m = fmaxf(m, __shfl_xor(m, o));
    if ((tid & 63) == 0) rmax[tid >> 6] = m;
    __syncthreads();
    m = fmaxf(fmaxf(rmax[0], rmax[1]), fmaxf(rmax[2], rmax[3]));
    float p0 = __expf(e0 - m), p1 = __expf(e1 - m);
    float ss = p0 + p1;
    for (int o = 32; o > 0; o >>= 1) ss += __shfl_xor(ss, o);
    if ((tid & 63) == 0) rsum[tid >> 6] = ss;
    __syncthreads();
    ss = rsum[0] + rsum[1] + rsum[2] + rsum[3];
    float inv = __fdividef(1.0f, ss);
    out[b * 512 + tid] = p0 * inv;
    out[b * 512 + 256 + tid] = p1 * inv;
}

extern "C" void kernel_launch(void* const* d_in, const int* in_sizes, int n_in,
                              void* d_out, int out_size, void* d_ws, size_t ws_size,
                              hipStream_t stream) {
    const float* hidden = (const float*)d_in[0];
    const float* cell   = (const float*)d_in[1];
    const float* X      = (const float*)d_in[2];
    const float* We1    = (const float*)d_in[3];
    const float* be1    = (const float*)d_in[4];
    const float* We2    = (const float*)d_in[5];
    const float* be2    = (const float*)d_in[6];
    const float* v      = (const float*)d_in[7];
    float* out = (float*)d_out;

    char* ws = (char*)d_ws;
    _Float16* Af = (_Float16*)ws;                        // 512*512*2   = 524288 B
    float* g     = (float*)(ws + 524288);                // 128*512*4   = 262144 B
    float* Ep    = (float*)(ws + 786432);                // 2*128*512*4 = 524288 B

    k_prep_a<<<16, 256, 0, stream>>>(We2, Af);
    k_hs<<<128, 256, 0, stream>>>(hidden, cell, We1, be1, be2, g);
    k_main<<<2048, 256, 0, stream>>>(X, Af, g, v, Ep);
    k_softmax<<<128, 256, 0, stream>>>(Ep, out);
}

// Round 13
// 80.947 us; speedup vs baseline: 1.1574x; 1.0282x over previous
//
#include <hip/hip_runtime.h>
#include <hip/hip_bf16.h>

// Problem: B=128, M=256, T=512, N=512
// D[k][n] = sum_t We2T[k][t]*X[t][n] per b; e[b,n] = sum_k tanh(D+g[b,k])*v[k];
// attn = softmax_n(e).  k split in 2 block-halves (kblk); partials summed in
// softmax (k-sum is outside tanh).
// R13: ALL staging via global_load_lds so the VMEM queue holds DMAs only, in
// tile order -> counted vmcnt works (R12 bug: frag-direct global reads at the
// queue tail forced vmcnt(0) drains every step).

typedef _Float16 half8 __attribute__((ext_vector_type(8)));
typedef _Float16 half2v __attribute__((ext_vector_type(2)));
typedef float floatx4 __attribute__((ext_vector_type(4)));

#define GLOAD_LDS16(gp, lp) __builtin_amdgcn_global_load_lds(                  \
    (const __attribute__((address_space(1))) void*)(const void*)(gp),          \
    (__attribute__((address_space(3))) void*)(void*)(lp), 16, 0, 0)

__device__ __forceinline__ float fast_tanh(float x) {
    float cx = fminf(15.0f, fmaxf(-15.0f, x));
    float e = __expf(2.0f * cx);
    return (e - 1.0f) * __fdividef(1.0f, e + 1.0f);
}

// ---------------- K0: Af slabs (A = We2^T f16, frag-linear) ----------------
// slab ts (32 t), chunk c = k-16-group (0..31), lane l: holds
// A[k=c*16+(l&15)][t=ts*32+(l>>4)*8+j], j=0..7.  Elem ofs: ts*16384+c*512+l*8.
__global__ __launch_bounds__(256) void k_prep_a(const float* __restrict__ We2,
                                                _Float16* __restrict__ Af) {
    __shared__ float w2[32][512];
    const int ts = blockIdx.x;
    for (int idx = threadIdx.x; idx < 32 * 512; idx += 256) {
        int tl = idx >> 9, k = idx & 511;
        w2[tl][k] = We2[(ts * 32 + tl) * 512 + k];
    }
    __syncthreads();
    for (int item = threadIdx.x; item < 32 * 64; item += 256) {
        int c = item >> 6, l = item & 63;
        int k  = c * 16 + (l & 15);
        int tl = (l >> 4) * 8;
        half8 h;
#pragma unroll
        for (int j = 0; j < 8; ++j) h[j] = (_Float16)w2[tl + j][k];
        *(half8*)&Af[(((size_t)ts * 32 + c) * 64 + l) * 8] = h;
    }
}

// ---------------- K1: g[b][k] = hc@We1 + be1 + be2 ----------------
__global__ __launch_bounds__(256) void k_hs(const float* __restrict__ hidden,
                                            const float* __restrict__ cell,
                                            const float* __restrict__ We1,
                                            const float* __restrict__ be1,
                                            const float* __restrict__ be2,
                                            float* __restrict__ g) {
    __shared__ __align__(16) float hcl[8][512];
    __shared__ float red[4][8][64];
    const int b0 = (blockIdx.x >> 3) << 3;
    const int k0 = (blockIdx.x & 7) << 6;
    for (int idx = threadIdx.x; idx < 8 * 512; idx += 256) {
        int bi = idx >> 9, j = idx & 511;
        hcl[bi][j] = (j < 256) ? hidden[(b0 + bi) * 256 + j]
                               : cell[(b0 + bi) * 256 + j - 256];
    }
    __syncthreads();
    const int kl = threadIdx.x & 63;
    const int jc = threadIdx.x >> 6;
    const int k  = k0 + kl;
    float acc[8] = {};
    for (int j = jc * 128; j < jc * 128 + 128; j += 4) {
        float w0 = We1[(j + 0) * 512 + k];
        float w1 = We1[(j + 1) * 512 + k];
        float w2 = We1[(j + 2) * 512 + k];
        float w3 = We1[(j + 3) * 512 + k];
#pragma unroll
        for (int bi = 0; bi < 8; ++bi) {
            float4 h = *(const float4*)&hcl[bi][j];
            acc[bi] += h.x * w0 + h.y * w1 + h.z * w2 + h.w * w3;
        }
    }
#pragma unroll
    for (int bi = 0; bi < 8; ++bi) red[jc][bi][kl] = acc[bi];
    __syncthreads();
    for (int idx = threadIdx.x; idx < 512; idx += 256) {
        int bi = idx >> 6, kk = idx & 63;
        float s = red[0][bi][kk] + red[1][bi][kk] + red[2][bi][kk] + red[3][bi][kk];
        int kg = k0 + kk;
        g[(b0 + bi) * 512 + kg] = s + be1[kg] + be2[kg];
    }
}

// ---------------- K2: fused GEMM, BK=32, clean-queue DMA pipeline -----------
// grid 2048 = 128b x 8nt(64) x 2kblk(256), XCD chunk-swizzle (kblk-siblings
// co-XCD).  256 thr = 4 waves: kw=wv&1 (k-128-half), nw=wv>>1 (n-32-half);
// wave tile 128k x 32n = 8kf x 2nf = 16 MFMA/step, 16 steps.
// A slab [16 c][512] f16 single-buf 16 KB (overwrite guarded by lgkm+barrier);
// X [32t][16c][4n] f32 3-buf 24 KB (src chunk-XOR c^=((t>>3)&3)<<1, matched
// on read => 2-way banks).  Queue/step = [X(s):2][A(s):4][X(s+1):2] ->
// vmcnt(2) at top.  40 KB LDS -> 4 blocks/CU.
__global__ __launch_bounds__(256, 4) void k_main(const float* __restrict__ X,
                                                 const _Float16* __restrict__ Af,
                                                 const float* __restrict__ g,
                                                 const float* __restrict__ vvec,
                                                 float* __restrict__ Ep) {
    __shared__ __align__(16) _Float16 Ab[8192];      // 16 KB
    __shared__ __align__(16) float    Xs[3][2048];   // 3 x 8 KB
    const int tid  = threadIdx.x;
    const int lane = tid & 63;
    const int wv   = tid >> 6;        // 0..3
    const int l16  = lane & 15;
    const int lhi  = lane >> 4;       // 0..3
    const int kw   = wv & 1;          // k-half (128)
    const int nw   = wv >> 1;         // n-half (32)
    const int logical = (blockIdx.x & 7) * 256 + (blockIdx.x >> 3);
    const int kblk = logical & 1;
    const int nt   = (logical >> 1) & 7;
    const int b    = logical >> 4;
    const int n0   = nt << 6;

    const float* Xg = X + (size_t)b * 262144 + n0;
    const _Float16* Ag = Af + (size_t)(kblk * 16 + wv * 4) * 512 + (size_t)lane * 8;

    // X-DMA: wave wv covers t-rows [wv*8, wv*8+8) of the 32-t tile, 2 instrs.
    int xsrc[2], xdst[2];
#pragma unroll
    for (int p = 0; p < 2; ++p) {
        int t_loc = wv * 8 + p * 4 + (lane >> 4);
        int c_g   = (lane & 15) ^ (((t_loc >> 3) & 3) << 1);
        xsrc[p] = t_loc * 512 + c_g * 4;                  // f32 elems
        xdst[p] = (wv * 8 + p * 4) * 64 + lane * 4;       // linear 16B/lane
    }
#define XDMA(s_, b_)                                                           \
    { _Pragma("unroll")                                                        \
      for (int p = 0; p < 2; ++p)                                              \
          GLOAD_LDS16(Xg + (size_t)(s_) * 16384 + xsrc[p], &Xs[b_][xdst[p]]); }
#define ADMA(s_)                                                               \
    { _Pragma("unroll")                                                        \
      for (int i = 0; i < 4; ++i)                                              \
          GLOAD_LDS16(Ag + (size_t)(s_) * 16384 + i * 512,                     \
                      &Ab[(wv * 4 + i) * 512 + lane * 8]); }

    // X-read geometry: nf_eff = nw*2+nf, c_read = (nf_eff*4+q)^(lhi<<1)
    const int q = l16 >> 2, r = l16 & 3;
    int boff[2];
#pragma unroll
    for (int nf = 0; nf < 2; ++nf) {
        int nfe = nw * 2 + nf;
        boff[nf] = lhi * 512 + ((((nfe << 2) + q) ^ (lhi << 1)) << 2) + r;
    }

    // ---- prologue: queue = [X0:2][A0:4][X1:2]
    XDMA(0, 0);
    ADMA(0);
    XDMA(1, 1);

    floatx4 acc[8][2];
#pragma unroll
    for (int a = 0; a < 8; ++a) {
        acc[a][0] = (floatx4){0.f, 0.f, 0.f, 0.f};
        acc[a][1] = (floatx4){0.f, 0.f, 0.f, 0.f};
    }

#pragma unroll
    for (int s = 0; s < 16; ++s) {
        const int buf = s % 3;
        // top: X(s)+A(s) landed; X(s+1) stays in flight
        if (s < 15) asm volatile("s_waitcnt vmcnt(2)" ::: "memory");
        else        asm volatile("s_waitcnt vmcnt(0)" ::: "memory");
        __builtin_amdgcn_sched_barrier(0);
        __builtin_amdgcn_s_barrier();
        __builtin_amdgcn_sched_barrier(0);
        // fragment reads: A 8 x b128 (conflict-free), X 16 x b32 (2-way) + cvt
        half8 af[8];
#pragma unroll
        for (int kf = 0; kf < 8; ++kf)
            af[kf] = *(const half8*)&Ab[(kw * 8 + kf) * 512 + lane * 8];
        half8 bf[2];
#pragma unroll
        for (int nf = 0; nf < 2; ++nf) {
            union { half2v h2[4]; half8 h8; } u;
#pragma unroll
            for (int m = 0; m < 4; ++m) {
                float f0 = Xs[buf][boff[nf] + (2 * m) * 64];
                float f1 = Xs[buf][boff[nf] + (2 * m + 1) * 64];
                u.h2[m] = __builtin_bit_cast(half2v,
                              __builtin_amdgcn_cvt_pkrtz(f0, f1));
            }
            bf[nf] = u.h8;
        }
        // reads drained -> safe to overwrite A-buf / X-buf after barrier
        asm volatile("s_waitcnt lgkmcnt(0)" ::: "memory");
        __builtin_amdgcn_sched_barrier(0);
        __builtin_amdgcn_s_barrier();
        __builtin_amdgcn_sched_barrier(0);
        // issue next DMAs (queue stays in tile order)
        if (s < 15) ADMA(s + 1);
        if (s < 14) XDMA(s + 2, (s + 2) % 3);
        __builtin_amdgcn_sched_barrier(0);
        // MFMA cluster (registers only)
        __builtin_amdgcn_s_setprio(1);
#pragma unroll
        for (int kf = 0; kf < 8; ++kf) {
            acc[kf][0] = __builtin_amdgcn_mfma_f32_16x16x32_f16(af[kf], bf[0], acc[kf][0], 0, 0, 0);
            acc[kf][1] = __builtin_amdgcn_mfma_f32_16x16x32_f16(af[kf], bf[1], acc[kf][1], 0, 0, 0);
        }
        __builtin_amdgcn_s_setprio(0);
    }
#undef XDMA
#undef ADMA

    // ---- fused epilogue: s[n] = sum_{k in wave 128-slice} tanh(acc+g)*v
    // D layout: row k = lhi*4+reg (in 16-group kf), col n = l16
    const float* gb = g + b * 512;
    float s0 = 0.f, s1 = 0.f;
#pragma unroll
    for (int kf = 0; kf < 8; ++kf) {
        const int kb = kblk * 256 + kw * 128 + kf * 16 + lhi * 4;
        float g0 = gb[kb + 0], g1 = gb[kb + 1], g2 = gb[kb + 2], g3 = gb[kb + 3];
        float v0 = vvec[kb + 0], v1 = vvec[kb + 1], v2 = vvec[kb + 2], v3 = vvec[kb + 3];
        s0 += fast_tanh(acc[kf][0][0] + g0) * v0;
        s0 += fast_tanh(acc[kf][0][1] + g1) * v1;
        s0 += fast_tanh(acc[kf][0][2] + g2) * v2;
        s0 += fast_tanh(acc[kf][0][3] + g3) * v3;
        s1 += fast_tanh(acc[kf][1][0] + g0) * v0;
        s1 += fast_tanh(acc[kf][1][1] + g1) * v1;
        s1 += fast_tanh(acc[kf][1][2] + g2) * v2;
        s1 += fast_tanh(acc[kf][1][3] + g3) * v3;
    }
    s0 += __shfl_xor(s0, 16);  s0 += __shfl_xor(s0, 32);
    s1 += __shfl_xor(s1, 16);  s1 += __shfl_xor(s1, 32);

    __syncthreads();                 // loop fully drained -> overlay on Ab
    float* ered = (float*)&Ab[0];    // [2 kw][64 n]
    if (lane < 16) {
        ered[kw * 64 + nw * 32 + 0  + l16] = s0;
        ered[kw * 64 + nw * 32 + 16 + l16] = s1;
    }
    __syncthreads();
    if (tid < 64) {
        float e = ered[tid] + ered[64 + tid];
        Ep[(size_t)kblk * 65536 + b * 512 + n0 + tid] = e;
    }
}

// ---------------- K3: softmax over n (512), summing 2 k-partials ------------
__global__ __launch_bounds__(256) void k_softmax(const float* __restrict__ Ep,
                                                 float* __restrict__ out) {
    __shared__ float rmax[4], rsum[4];
    const int b = blockIdx.x;
    const int tid = threadIdx.x;
    const float* E0 = Ep;
    const float* E1 = Ep + 65536;
    float e0 = E0[b * 512 + tid] + E1[b * 512 + tid];
    float e1 = E0[b * 512 + 256 + tid] + E1[b * 512 + 256 + tid];
    float m = fmaxf(e0, e1);
    for (int o = 32; o > 0; o >>= 1) m = fmaxf(m, __shfl_xor(m, o));
    if ((tid & 63) == 0) rmax[tid >> 6] = m;
    __syncthreads();
    m = fmaxf(fmaxf(rmax[0], rmax[1]), fmaxf(rmax[2], rmax[3]));
    float p0 = __expf(e0 - m), p1 = __expf(e1 - m);
    float ss = p0 + p1;
    for (int o = 32; o > 0; o >>= 1) ss += __shfl_xor(ss, o);
    if ((tid & 63) == 0) rsum[tid >> 6] = ss;
    __syncthreads();
    ss = rsum[0] + rsum[1] + rsum[2] + rsum[3];
    float inv = __fdividef(1.0f, ss);
    out[b * 512 + tid] = p0 * inv;
    out[b * 512 + 256 + tid] = p1 * inv;
}

extern "C" void kernel_launch(void* const* d_in, const int* in_sizes, int n_in,
                              void* d_out, int out_size, void* d_ws, size_t ws_size,
                              hipStream_t stream) {
    const float* hidden = (const float*)d_in[0];
    const float* cell   = (const float*)d_in[1];
    const float* X      = (const float*)d_in[2];
    const float* We1    = (const float*)d_in[3];
    const float* be1    = (const float*)d_in[4];
    const float* We2    = (const float*)d_in[5];
    const float* be2    = (const float*)d_in[6];
    const float* v      = (const float*)d_in[7];
    float* out = (float*)d_out;

    char* ws = (char*)d_ws;
    _Float16* Af = (_Float16*)ws;                        // 512*512*2   = 524288 B
    float* g     = (float*)(ws + 524288);                // 128*512*4   = 262144 B
    float* Ep    = (float*)(ws + 786432);                // 2*128*512*4 = 524288 B

    k_prep_a<<<16, 256, 0, stream>>>(We2, Af);
    k_hs<<<128, 256, 0, stream>>>(hidden, cell, We1, be1, be2, g);
    k_main<<<2048, 256, 0, stream>>>(X, Af, g, v, Ep);
    k_softmax<<<128, 256, 0, stream>>>(Ep, out);
}

// Round 14
// 78.417 us; speedup vs baseline: 1.1947x; 1.0323x over previous
//
#include <hip/hip_runtime.h>
#include <hip/hip_bf16.h>

// Problem: B=128, M=256, T=512, N=512
// D[k][n] = sum_t We2T[k][t]*X[t][n] per b; e[b,n] = sum_k tanh(D+g[b,k])*v[k];
// attn = softmax_n(e).  k split in 2 block-halves (kblk); partials summed in
// softmax.
// R14: LDS-traffic-minimal. A (We2, L2-hot) frag-direct global->reg, never in
// LDS.  X staged f16 with free transpose (thread loads a t-run down one n
// column, coalesced across lanes; ds_write_b128 makes LDS t-contiguous) ->
// X fragments are single b128 reads.  LDS per block-step: 72 KB -> 20 KB.

typedef _Float16 half8 __attribute__((ext_vector_type(8)));
typedef float floatx4 __attribute__((ext_vector_type(4)));

__device__ __forceinline__ float fast_tanh(float x) {
    float cx = fminf(15.0f, fmaxf(-15.0f, x));
    float e = __expf(2.0f * cx);
    return (e - 1.0f) * __fdividef(1.0f, e + 1.0f);
}

// ---------------- K0: Af slabs (A = We2^T f16, frag-linear) ----------------
// slab ts (32 t), chunk c = k-16-group (0..31), lane l: holds
// A[k=c*16+(l&15)][t=ts*32+(l>>4)*8+j], j=0..7.  Elem ofs: ts*16384+c*512+l*8.
__global__ __launch_bounds__(256) void k_prep_a(const float* __restrict__ We2,
                                                _Float16* __restrict__ Af) {
    __shared__ float w2[32][512];
    const int ts = blockIdx.x;
    for (int idx = threadIdx.x; idx < 32 * 512; idx += 256) {
        int tl = idx >> 9, k = idx & 511;
        w2[tl][k] = We2[(ts * 32 + tl) * 512 + k];
    }
    __syncthreads();
    for (int item = threadIdx.x; item < 32 * 64; item += 256) {
        int c = item >> 6, l = item & 63;
        int k  = c * 16 + (l & 15);
        int tl = (l >> 4) * 8;
        half8 h;
#pragma unroll
        for (int j = 0; j < 8; ++j) h[j] = (_Float16)w2[tl + j][k];
        *(half8*)&Af[(((size_t)ts * 32 + c) * 64 + l) * 8] = h;
    }
}

// ---------------- K1: g[b][k] = hc@We1 + be1 + be2 ----------------
__global__ __launch_bounds__(256) void k_hs(const float* __restrict__ hidden,
                                            const float* __restrict__ cell,
                                            const float* __restrict__ We1,
                                            const float* __restrict__ be1,
                                            const float* __restrict__ be2,
                                            float* __restrict__ g) {
    __shared__ __align__(16) float hcl[8][512];
    __shared__ float red[4][8][64];
    const int b0 = (blockIdx.x >> 3) << 3;
    const int k0 = (blockIdx.x & 7) << 6;
    for (int idx = threadIdx.x; idx < 8 * 512; idx += 256) {
        int bi = idx >> 9, j = idx & 511;
        hcl[bi][j] = (j < 256) ? hidden[(b0 + bi) * 256 + j]
                               : cell[(b0 + bi) * 256 + j - 256];
    }
    __syncthreads();
    const int kl = threadIdx.x & 63;
    const int jc = threadIdx.x >> 6;
    const int k  = k0 + kl;
    float acc[8] = {};
    for (int j = jc * 128; j < jc * 128 + 128; j += 4) {
        float w0 = We1[(j + 0) * 512 + k];
        float w1 = We1[(j + 1) * 512 + k];
        float w2 = We1[(j + 2) * 512 + k];
        float w3 = We1[(j + 3) * 512 + k];
#pragma unroll
        for (int bi = 0; bi < 8; ++bi) {
            float4 h = *(const float4*)&hcl[bi][j];
            acc[bi] += h.x * w0 + h.y * w1 + h.z * w2 + h.w * w3;
        }
    }
#pragma unroll
    for (int bi = 0; bi < 8; ++bi) red[jc][bi][kl] = acc[bi];
    __syncthreads();
    for (int idx = threadIdx.x; idx < 512; idx += 256) {
        int bi = idx >> 6, kk = idx & 63;
        float s = red[0][bi][kk] + red[1][bi][kk] + red[2][bi][kk] + red[3][bi][kk];
        int kg = k0 + kk;
        g[(b0 + bi) * 512 + kg] = s + be1[kg] + be2[kg];
    }
}

// ---------------- K2: fused GEMM, lean-LDS, BK=32 ----------------
// grid 2048 = 128b x 8nt(64n) x 2kblk(256k), XCD chunk-swizzle.  256 thr =
// 4 waves; wave wv owns k [kblk*256+wv*64,+64) x 64n -> acc 4x4 = 16 MFMA /
// step, 16 steps.  A frag-direct global b128 (L2-hot Af, no LDS).  X: f16
// LDS dbuf 2x4KB [64n][32t] t-contiguous (transpose free in staging),
// XOR-slot swizzle, b128 frag reads.  X loads 3-set-deep in regs.
__global__ __launch_bounds__(256, 3) void k_main(const float* __restrict__ X,
                                                 const _Float16* __restrict__ Af,
                                                 const float* __restrict__ g,
                                                 const float* __restrict__ vvec,
                                                 float* __restrict__ Ep) {
    __shared__ __align__(16) _Float16 Xb[2][2048];   // 2 x 4 KB
    const int tid  = threadIdx.x;
    const int lane = tid & 63;
    const int wv   = tid >> 6;        // 0..3
    const int l16  = lane & 15;
    const int lhi  = lane >> 4;       // 0..3
    const int logical = (blockIdx.x & 7) * 256 + (blockIdx.x >> 3);
    const int kblk = logical & 1;
    const int nt   = (logical >> 1) & 7;
    const int b    = logical >> 4;
    const int n0   = nt << 6;

    const float* Xg = X + (size_t)b * 262144 + n0;
    // A frag base: chunk c = kblk*16 + wv*4 + kf; + s*16384 + kf*512 elems
    const _Float16* Ag = Af + (size_t)(kblk * 16 + wv * 4) * 512 + (size_t)lane * 8;

    // X staging: thread (xn = tid&63 -> n, xo = tid>>6 -> t-octet).
    const int xn = tid & 63;
    const int xo = tid >> 6;
    const float* Xt = Xg + (size_t)(xo * 8) * 512 + xn;   // + s*16384 + j*512
    // LDS slot (f16 elems): row n (32 f16), t-octet slot XOR-swizzled.
    const int wslot = xn * 32 + ((xo ^ (xn & 3) ^ ((xn >> 2) & 3)) << 3);
    int roff[4];
#pragma unroll
    for (int nf = 0; nf < 4; ++nf) {
        int n = nf * 16 + l16;
        roff[nf] = n * 32 + ((lhi ^ (n & 3) ^ ((n >> 2) & 3)) << 3);
    }

    float xs0[8], xs1[8], xs2[8];     // X(m) lives in set m%3
#define XLOAD(s_, arr_)                                                        \
    do { _Pragma("unroll")                                                     \
         for (int j = 0; j < 8; ++j)                                           \
             arr_[j] = Xt[(size_t)(s_) * 16384 + (size_t)j * 512];             \
    } while (0)
#define XSTORE(s_, arr_)                                                       \
    do { half8 h;                                                              \
         _Pragma("unroll")                                                     \
         for (int j = 0; j < 8; ++j) h[j] = (_Float16)arr_[j];                 \
         *(half8*)&Xb[(s_) & 1][wslot] = h;                                    \
    } while (0)

    // ---- prologue: X(0),X(1),X(2) in flight; X(0) -> Xb[0]
    XLOAD(0, xs0);
    XLOAD(1, xs1);
    XLOAD(2, xs2);
    XSTORE(0, xs0);                   // waits X(0) only (X1,X2 newer, stay)
    asm volatile("s_waitcnt lgkmcnt(0)" ::: "memory");
    __builtin_amdgcn_sched_barrier(0);
    __builtin_amdgcn_s_barrier();
    __builtin_amdgcn_sched_barrier(0);

    floatx4 acc[4][4];
#pragma unroll
    for (int a = 0; a < 4; ++a)
#pragma unroll
        for (int c = 0; c < 4; ++c) acc[a][c] = (floatx4){0.f, 0.f, 0.f, 0.f};

#pragma unroll
    for (int s = 0; s < 16; ++s) {
        const int cur = s & 1;
        // 1. A(s) frags: 4 coalesced b128 from L2-hot Af (oldest new VMEM ->
        //    MFMA's wait leaves X loads issued after in flight)
        half8 af[4];
#pragma unroll
        for (int kf = 0; kf < 4; ++kf)
            af[kf] = *(const half8*)(Ag + (size_t)s * 16384 + (size_t)kf * 512);
        // 2. issue X(s+3) into reg set (s%3)
        if (s + 3 < 16) {
            if ((s % 3) == 0)      XLOAD(s + 3, xs0);
            else if ((s % 3) == 1) XLOAD(s + 3, xs1);
            else                   XLOAD(s + 3, xs2);
        }
        // 3. X(s) fragments: 4 x ds_read_b128 (swizzled, even-spread)
        half8 bf[4];
#pragma unroll
        for (int nf = 0; nf < 4; ++nf)
            bf[nf] = *(const half8*)&Xb[cur][roff[nf]];
        // 4. cvt + write X(s+1) (regs landed 2 steps ago) into Xb[cur^1]
        if (s + 1 < 16) {
            if (((s + 1) % 3) == 0)      XSTORE(s + 1, xs0);
            else if (((s + 1) % 3) == 1) XSTORE(s + 1, xs1);
            else                         XSTORE(s + 1, xs2);
        }
        // 5. MFMA cluster
        __builtin_amdgcn_s_setprio(1);
#pragma unroll
        for (int kf = 0; kf < 4; ++kf)
#pragma unroll
            for (int nf = 0; nf < 4; ++nf)
                acc[kf][nf] = __builtin_amdgcn_mfma_f32_16x16x32_f16(
                    af[kf], bf[nf], acc[kf][nf], 0, 0, 0);
        __builtin_amdgcn_s_setprio(0);
        // 6. LDS-only drain + barrier (no vmcnt: X loads stay in flight)
        asm volatile("s_waitcnt lgkmcnt(0)" ::: "memory");
        __builtin_amdgcn_sched_barrier(0);
        __builtin_amdgcn_s_barrier();
        __builtin_amdgcn_sched_barrier(0);
    }
#undef XLOAD
#undef XSTORE

    // ---- fused epilogue: s[n] = sum_{k slice} tanh(acc+g)*v
    // D layout: row k = lhi*4+reg (within kf 16-group), col n = l16
    const float* gb = g + b * 512;
    float sacc[4] = {0.f, 0.f, 0.f, 0.f};
#pragma unroll
    for (int kf = 0; kf < 4; ++kf) {
        const int kb = kblk * 256 + wv * 64 + kf * 16 + lhi * 4;
        float g0 = gb[kb + 0], g1 = gb[kb + 1], g2 = gb[kb + 2], g3 = gb[kb + 3];
        float v0 = vvec[kb + 0], v1 = vvec[kb + 1], v2 = vvec[kb + 2], v3 = vvec[kb + 3];
#pragma unroll
        for (int nf = 0; nf < 4; ++nf) {
            sacc[nf] += fast_tanh(acc[kf][nf][0] + g0) * v0;
            sacc[nf] += fast_tanh(acc[kf][nf][1] + g1) * v1;
            sacc[nf] += fast_tanh(acc[kf][nf][2] + g2) * v2;
            sacc[nf] += fast_tanh(acc[kf][nf][3] + g3) * v3;
        }
    }
#pragma unroll
    for (int nf = 0; nf < 4; ++nf) {
        sacc[nf] += __shfl_xor(sacc[nf], 16);
        sacc[nf] += __shfl_xor(sacc[nf], 32);
    }
    __syncthreads();                 // loop done -> overlay on Xb
    float* ered = (float*)&Xb[0][0]; // [4 waves][64 n]
    if (lane < 16) {
#pragma unroll
        for (int nf = 0; nf < 4; ++nf) ered[wv * 64 + nf * 16 + l16] = sacc[nf];
    }
    __syncthreads();
    if (tid < 64) {
        float e = ered[tid] + ered[64 + tid] + ered[128 + tid] + ered[192 + tid];
        Ep[(size_t)kblk * 65536 + b * 512 + n0 + tid] = e;
    }
}

// ---------------- K3: softmax over n (512), summing 2 k-partials ------------
__global__ __launch_bounds__(256) void k_softmax(const float* __restrict__ Ep,
                                                 float* __restrict__ out) {
    __shared__ float rmax[4], rsum[4];
    const int b = blockIdx.x;
    const int tid = threadIdx.x;
    const float* E0 = Ep;
    const float* E1 = Ep + 65536;
    float e0 = E0[b * 512 + tid] + E1[b * 512 + tid];
    float e1 = E0[b * 512 + 256 + tid] + E1[b * 512 + 256 + tid];
    float m = fmaxf(e0, e1);
    for (int o = 32; o > 0; o >>= 1) m = fmaxf(m, __shfl_xor(m, o));
    if ((tid & 63) == 0) rmax[tid >> 6] = m;
    __syncthreads();
    m = fmaxf(fmaxf(rmax[0], rmax[1]), fmaxf(rmax[2], rmax[3]));
    float p0 = __expf(e0 - m), p1 = __expf(e1 - m);
    float ss = p0 + p1;
    for (int o = 32; o > 0; o >>= 1) ss += __shfl_xor(ss, o);
    if ((tid & 63) == 0) rsum[tid >> 6] = ss;
    __syncthreads();
    ss = rsum[0] + rsum[1] + rsum[2] + rsum[3];
    float inv = __fdividef(1.0f, ss);
    out[b * 512 + tid] = p0 * inv;
    out[b * 512 + 256 + tid] = p1 * inv;
}

extern "C" void kernel_launch(void* const* d_in, const int* in_sizes, int n_in,
                              void* d_out, int out_size, void* d_ws, size_t ws_size,
                              hipStream_t stream) {
    const float* hidden = (const float*)d_in[0];
    const float* cell   = (const float*)d_in[1];
    const float* X      = (const float*)d_in[2];
    const float* We1    = (const float*)d_in[3];
    const float* be1    = (const float*)d_in[4];
    const float* We2    = (const float*)d_in[5];
    const float* be2    = (const float*)d_in[6];
    const float* v      = (const float*)d_in[7];
    float* out = (float*)d_out;

    char* ws = (char*)d_ws;
    _Float16* Af = (_Float16*)ws;                        // 512*512*2   = 524288 B
    float* g     = (float*)(ws + 524288);                // 128*512*4   = 262144 B
    float* Ep    = (float*)(ws + 786432);                // 2*128*512*4 = 524288 B

    k_prep_a<<<16, 256, 0, stream>>>(We2, Af);
    k_hs<<<128, 256, 0, stream>>>(hidden, cell, We1, be1, be2, g);
    k_main<<<2048, 256, 0, stream>>>(X, Af, g, v, Ep);
    k_softmax<<<128, 256, 0, stream>>>(Ep, out);
}

// Round 15
// 76.786 us; speedup vs baseline: 1.2201x; 1.0212x over previous
//
#include <hip/hip_runtime.h>
#include <hip/hip_bf16.h>

// Problem: B=128, M=256, T=512, N=512
// D[k][n] = sum_t We2T[k][t]*X[t][n] per b; e[b,n] = sum_k tanh(D+g[b,k])*v[k];
// attn = softmax_n(e).  k split in 2 block-halves (kblk); partials summed in
// softmax.
// R15 = R14 + A-fragment register double-buffer ONE STEP AHEAD (the remaining
// per-step exposed latency).  Queue per step = [A(s+1):4][X(s+3):8], all newer
// than any waited-on value -> compiler's positional vmcnt waits keep them in
// flight; s_barrier asm (memory clobber) stops cross-step sinking.

typedef _Float16 half8 __attribute__((ext_vector_type(8)));
typedef float floatx4 __attribute__((ext_vector_type(4)));

__device__ __forceinline__ float fast_tanh(float x) {
    float cx = fminf(15.0f, fmaxf(-15.0f, x));
    float e = __expf(2.0f * cx);
    return (e - 1.0f) * __fdividef(1.0f, e + 1.0f);
}

// ---------------- K0: Af slabs (A = We2^T f16, frag-linear) ----------------
// slab ts (32 t), chunk c = k-16-group (0..31), lane l: holds
// A[k=c*16+(l&15)][t=ts*32+(l>>4)*8+j], j=0..7.  Elem ofs: ts*16384+c*512+l*8.
__global__ __launch_bounds__(256) void k_prep_a(const float* __restrict__ We2,
                                                _Float16* __restrict__ Af) {
    __shared__ float w2[32][512];
    const int ts = blockIdx.x;
    for (int idx = threadIdx.x; idx < 32 * 512; idx += 256) {
        int tl = idx >> 9, k = idx & 511;
        w2[tl][k] = We2[(ts * 32 + tl) * 512 + k];
    }
    __syncthreads();
    for (int item = threadIdx.x; item < 32 * 64; item += 256) {
        int c = item >> 6, l = item & 63;
        int k  = c * 16 + (l & 15);
        int tl = (l >> 4) * 8;
        half8 h;
#pragma unroll
        for (int j = 0; j < 8; ++j) h[j] = (_Float16)w2[tl + j][k];
        *(half8*)&Af[(((size_t)ts * 32 + c) * 64 + l) * 8] = h;
    }
}

// ---------------- K1: g[b][k] = hc@We1 + be1 + be2 ----------------
__global__ __launch_bounds__(256) void k_hs(const float* __restrict__ hidden,
                                            const float* __restrict__ cell,
                                            const float* __restrict__ We1,
                                            const float* __restrict__ be1,
                                            const float* __restrict__ be2,
                                            float* __restrict__ g) {
    __shared__ __align__(16) float hcl[8][512];
    __shared__ float red[4][8][64];
    const int b0 = (blockIdx.x >> 3) << 3;
    const int k0 = (blockIdx.x & 7) << 6;
    for (int idx = threadIdx.x; idx < 8 * 512; idx += 256) {
        int bi = idx >> 9, j = idx & 511;
        hcl[bi][j] = (j < 256) ? hidden[(b0 + bi) * 256 + j]
                               : cell[(b0 + bi) * 256 + j - 256];
    }
    __syncthreads();
    const int kl = threadIdx.x & 63;
    const int jc = threadIdx.x >> 6;
    const int k  = k0 + kl;
    float acc[8] = {};
    for (int j = jc * 128; j < jc * 128 + 128; j += 4) {
        float w0 = We1[(j + 0) * 512 + k];
        float w1 = We1[(j + 1) * 512 + k];
        float w2 = We1[(j + 2) * 512 + k];
        float w3 = We1[(j + 3) * 512 + k];
#pragma unroll
        for (int bi = 0; bi < 8; ++bi) {
            float4 h = *(const float4*)&hcl[bi][j];
            acc[bi] += h.x * w0 + h.y * w1 + h.z * w2 + h.w * w3;
        }
    }
#pragma unroll
    for (int bi = 0; bi < 8; ++bi) red[jc][bi][kl] = acc[bi];
    __syncthreads();
    for (int idx = threadIdx.x; idx < 512; idx += 256) {
        int bi = idx >> 6, kk = idx & 63;
        float s = red[0][bi][kk] + red[1][bi][kk] + red[2][bi][kk] + red[3][bi][kk];
        int kg = k0 + kk;
        g[(b0 + bi) * 512 + kg] = s + be1[kg] + be2[kg];
    }
}

// ---------------- K2: fused GEMM, lean-LDS, BK=32, A reg-dbuf ----------------
// grid 2048 = 128b x 8nt(64n) x 2kblk(256k), XCD chunk-swizzle.  256 thr =
// 4 waves; wave wv owns k [kblk*256+wv*64,+64) x 64n -> acc 4x4 = 16 MFMA /
// step, 16 steps.  A: global b128 from L2-hot Af, REGISTER double-buffer one
// step ahead.  X: f16 LDS dbuf 2x4KB t-contiguous, XOR-slot swizzle, b128
// frag reads; X loads 3-set-deep in regs.
__global__ __launch_bounds__(256, 3) void k_main(const float* __restrict__ X,
                                                 const _Float16* __restrict__ Af,
                                                 const float* __restrict__ g,
                                                 const float* __restrict__ vvec,
                                                 float* __restrict__ Ep) {
    __shared__ __align__(16) _Float16 Xb[2][2048];   // 2 x 4 KB
    const int tid  = threadIdx.x;
    const int lane = tid & 63;
    const int wv   = tid >> 6;        // 0..3
    const int l16  = lane & 15;
    const int lhi  = lane >> 4;       // 0..3
    const int logical = (blockIdx.x & 7) * 256 + (blockIdx.x >> 3);
    const int kblk = logical & 1;
    const int nt   = (logical >> 1) & 7;
    const int b    = logical >> 4;
    const int n0   = nt << 6;

    const float* Xg = X + (size_t)b * 262144 + n0;
    const _Float16* Ag = Af + (size_t)(kblk * 16 + wv * 4) * 512 + (size_t)lane * 8;

    // X staging: thread (xn = tid&63 -> n, xo = tid>>6 -> t-octet).
    const int xn = tid & 63;
    const int xo = tid >> 6;
    const float* Xt = Xg + (size_t)(xo * 8) * 512 + xn;   // + s*16384 + j*512
    const int wslot = xn * 32 + ((xo ^ (xn & 3) ^ ((xn >> 2) & 3)) << 3);
    int roff[4];
#pragma unroll
    for (int nf = 0; nf < 4; ++nf) {
        int n = nf * 16 + l16;
        roff[nf] = n * 32 + ((lhi ^ (n & 3) ^ ((n >> 2) & 3)) << 3);
    }

    float xs0[8], xs1[8], xs2[8];     // X(m) lives in set m%3
#define XLOAD(s_, arr_)                                                        \
    do { _Pragma("unroll")                                                     \
         for (int j = 0; j < 8; ++j)                                           \
             arr_[j] = Xt[(size_t)(s_) * 16384 + (size_t)j * 512];             \
    } while (0)
#define XSTORE(s_, arr_)                                                       \
    do { half8 h;                                                              \
         _Pragma("unroll")                                                     \
         for (int j = 0; j < 8; ++j) h[j] = (_Float16)arr_[j];                 \
         *(half8*)&Xb[(s_) & 1][wslot] = h;                                    \
    } while (0)
#define ALOAD(s_, arr_)                                                        \
    do { _Pragma("unroll")                                                     \
         for (int kf = 0; kf < 4; ++kf)                                        \
             arr_[kf] = *(const half8*)(Ag + (size_t)(s_) * 16384 +            \
                                        (size_t)kf * 512);                     \
    } while (0)

    half8 afA[4], afB[4];

    // ---- prologue: X(0..2) + A(0) in flight; X(0) -> Xb[0]
    XLOAD(0, xs0);
    XLOAD(1, xs1);
    XLOAD(2, xs2);
    ALOAD(0, afA);
    XSTORE(0, xs0);                   // positional wait covers X(0) only
    asm volatile("s_waitcnt lgkmcnt(0)" ::: "memory");
    __builtin_amdgcn_sched_barrier(0);
    __builtin_amdgcn_s_barrier();
    __builtin_amdgcn_sched_barrier(0);

    floatx4 acc[4][4];
#pragma unroll
    for (int a = 0; a < 4; ++a)
#pragma unroll
        for (int c = 0; c < 4; ++c) acc[a][c] = (floatx4){0.f, 0.f, 0.f, 0.f};

#pragma unroll
    for (int s = 0; s < 16; ++s) {
        const int cur = s & 1;
        // 1. issue A(s+1) into the spare named set (newest VMEM before X)
        if (s + 1 < 16) {
            if ((s & 1) == 0) ALOAD(s + 1, afB);
            else              ALOAD(s + 1, afA);
        }
        // 2. issue X(s+3) into reg set (s%3)
        if (s + 3 < 16) {
            if ((s % 3) == 0)      XLOAD(s + 3, xs0);
            else if ((s % 3) == 1) XLOAD(s + 3, xs1);
            else                   XLOAD(s + 3, xs2);
        }
        __builtin_amdgcn_sched_barrier(0);   // pin issue block at step top
        // 3. X(s) fragments: 4 x ds_read_b128 (swizzled, even-spread)
        half8 bf[4];
#pragma unroll
        for (int nf = 0; nf < 4; ++nf)
            bf[nf] = *(const half8*)&Xb[cur][roff[nf]];
        // 4. cvt + write X(s+1) (regs landed 2 steps ago; counted wait leaves
        //    A(s+1)/X(s+3) in flight) into Xb[cur^1]
        if (s + 1 < 16) {
            if (((s + 1) % 3) == 0)      XSTORE(s + 1, xs0);
            else if (((s + 1) % 3) == 1) XSTORE(s + 1, xs1);
            else                         XSTORE(s + 1, xs2);
        }
        // 5. MFMA cluster with A(s) prefetched LAST step (no fresh latency)
        __builtin_amdgcn_s_setprio(1);
        if ((s & 1) == 0) {
#pragma unroll
            for (int kf = 0; kf < 4; ++kf)
#pragma unroll
                for (int nf = 0; nf < 4; ++nf)
                    acc[kf][nf] = __builtin_amdgcn_mfma_f32_16x16x32_f16(
                        afA[kf], bf[nf], acc[kf][nf], 0, 0, 0);
        } else {
#pragma unroll
            for (int kf = 0; kf < 4; ++kf)
#pragma unroll
                for (int nf = 0; nf < 4; ++nf)
                    acc[kf][nf] = __builtin_amdgcn_mfma_f32_16x16x32_f16(
                        afB[kf], bf[nf], acc[kf][nf], 0, 0, 0);
        }
        __builtin_amdgcn_s_setprio(0);
        // 6. LDS drain + barrier (no vmcnt: A/X prefetches stay in flight)
        asm volatile("s_waitcnt lgkmcnt(0)" ::: "memory");
        __builtin_amdgcn_sched_barrier(0);
        __builtin_amdgcn_s_barrier();
        __builtin_amdgcn_sched_barrier(0);
    }
#undef XLOAD
#undef XSTORE
#undef ALOAD

    // ---- fused epilogue: s[n] = sum_{k slice} tanh(acc+g)*v
    // D layout: row k = lhi*4+reg (within kf 16-group), col n = l16
    const float* gb = g + b * 512;
    float sacc[4] = {0.f, 0.f, 0.f, 0.f};
#pragma unroll
    for (int kf = 0; kf < 4; ++kf) {
        const int kb = kblk * 256 + wv * 64 + kf * 16 + lhi * 4;
        float g0 = gb[kb + 0], g1 = gb[kb + 1], g2 = gb[kb + 2], g3 = gb[kb + 3];
        float v0 = vvec[kb + 0], v1 = vvec[kb + 1], v2 = vvec[kb + 2], v3 = vvec[kb + 3];
#pragma unroll
        for (int nf = 0; nf < 4; ++nf) {
            sacc[nf] += fast_tanh(acc[kf][nf][0] + g0) * v0;
            sacc[nf] += fast_tanh(acc[kf][nf][1] + g1) * v1;
            sacc[nf] += fast_tanh(acc[kf][nf][2] + g2) * v2;
            sacc[nf] += fast_tanh(acc[kf][nf][3] + g3) * v3;
        }
    }
#pragma unroll
    for (int nf = 0; nf < 4; ++nf) {
        sacc[nf] += __shfl_xor(sacc[nf], 16);
        sacc[nf] += __shfl_xor(sacc[nf], 32);
    }
    __syncthreads();                 // loop done -> overlay on Xb
    float* ered = (float*)&Xb[0][0]; // [4 waves][64 n]
    if (lane < 16) {
#pragma unroll
        for (int nf = 0; nf < 4; ++nf) ered[wv * 64 + nf * 16 + l16] = sacc[nf];
    }
    __syncthreads();
    if (tid < 64) {
        float e = ered[tid] + ered[64 + tid] + ered[128 + tid] + ered[192 + tid];
        Ep[(size_t)kblk * 65536 + b * 512 + n0 + tid] = e;
    }
}

// ---------------- K3: softmax over n (512), summing 2 k-partials ------------
__global__ __launch_bounds__(256) void k_softmax(const float* __restrict__ Ep,
                                                 float* __restrict__ out) {
    __shared__ float rmax[4], rsum[4];
    const int b = blockIdx.x;
    const int tid = threadIdx.x;
    const float* E0 = Ep;
    const float* E1 = Ep + 65536;
    float e0 = E0[b * 512 + tid] + E1[b * 512 + tid];
    float e1 = E0[b * 512 + 256 + tid] + E1[b * 512 + 256 + tid];
    float m = fmaxf(e0, e1);
    for (int o = 32; o > 0; o >>= 1) m = fmaxf(m, __shfl_xor(m, o));
    if ((tid & 63) == 0) rmax[tid >> 6] = m;
    __syncthreads();
    m = fmaxf(fmaxf(rmax[0], rmax[1]), fmaxf(rmax[2], rmax[3]));
    float p0 = __expf(e0 - m), p1 = __expf(e1 - m);
    float ss = p0 + p1;
    for (int o = 32; o > 0; o >>= 1) ss += __shfl_xor(ss, o);
    if ((tid & 63) == 0) rsum[tid >> 6] = ss;
    __syncthreads();
    ss = rsum[0] + rsum[1] + rsum[2] + rsum[3];
    float inv = __fdividef(1.0f, ss);
    out[b * 512 + tid] = p0 * inv;
    out[b * 512 + 256 + tid] = p1 * inv;
}

extern "C" void kernel_launch(void* const* d_in, const int* in_sizes, int n_in,
                              void* d_out, int out_size, void* d_ws, size_t ws_size,
                              hipStream_t stream) {
    const float* hidden = (const float*)d_in[0];
    const float* cell   = (const float*)d_in[1];
    const float* X      = (const float*)d_in[2];
    const float* We1    = (const float*)d_in[3];
    const float* be1    = (const float*)d_in[4];
    const float* We2    = (const float*)d_in[5];
    const float* be2    = (const float*)d_in[6];
    const float* v      = (const float*)d_in[7];
    float* out = (float*)d_out;

    char* ws = (char*)d_ws;
    _Float16* Af = (_Float16*)ws;                        // 512*512*2   = 524288 B
    float* g     = (float*)(ws + 524288);                // 128*512*4   = 262144 B
    float* Ep    = (float*)(ws + 786432);                // 2*128*512*4 = 524288 B

    k_prep_a<<<16, 256, 0, stream>>>(We2, Af);
    k_hs<<<128, 256, 0, stream>>>(hidden, cell, We1, be1, be2, g);
    k_main<<<2048, 256, 0, stream>>>(X, Af, g, v, Ep);
    k_softmax<<<128, 256, 0, stream>>>(Ep, out);
}